// Round 9
// baseline (10217.567 us; speedup 1.0000x reference)
//
#include <hip/hip_runtime.h>
#include <hip/hip_bf16.h>
#include <math.h>

#define NB   32
#define FDIM 2048
#define VV   12000
#define DWW  300
#define HH   512
#define KW   3
#define TDEC 32
#define SEQ  33
#define NK   96
#define G4   2048
#define START_ID 1
#define END_ID   2
#define NROWS 3168
#define NZB  32      // fused select+Z+gates blocks
#define NLB  188     // logits blocks (64 cols each)
#define GRID 220
#define INTMX 0x7fffffff
#define FLOORF (-3.0e38f)
#define BAR_STRIDE 512   // ints per barrier: 8 shards x 64-int (256B) spacing
#define SHARD 64

typedef float f4v __attribute__((ext_vector_type(4)));
__device__ __forceinline__ void nt_store4(float* p, float4 v){
  f4v t; t.x=v.x; t.y=v.y; t.z=v.z; t.w=v.w;
  __builtin_nontemporal_store(t, (f4v*)p);
}

__device__ __forceinline__ float sigf(float x){ return 1.0f/(1.0f+expf(-x)); }

__device__ __forceinline__ unsigned short f2b(float x){
  __hip_bfloat16 b = __float2bfloat16(x);
  return *reinterpret_cast<unsigned short*>(&b);
}

// insert (v,i) into sorted-desc top3; tie -> smaller index wins
__device__ __forceinline__ void ins3(float v, int i, float tv[3], int ti[3]){
  if (v > tv[0] || (v == tv[0] && i < ti[0])){
    tv[2]=tv[1]; ti[2]=ti[1]; tv[1]=tv[0]; ti[1]=ti[0]; tv[0]=v; ti[0]=i;
  } else if (v > tv[1] || (v == tv[1] && i < ti[1])){
    tv[2]=tv[1]; ti[2]=ti[1]; tv[1]=v; ti[1]=i;
  } else if (v > tv[2] || (v == tv[2] && i < ti[2])){
    tv[2]=v; ti[2]=i;
  }
}

// producer: release-add to this block's shard
__device__ __forceinline__ void flag_arrive(int* f, int bid){
  __hip_atomic_fetch_add(f + (bid&7)*SHARD, 1, __ATOMIC_RELEASE, __HIP_MEMORY_SCOPE_AGENT);
}
// consumer: wave-0 acquire-poll of 8 shards, slow backoff (~1.7us between polls)
__device__ __forceinline__ void flag_wait(int* f, int target){
  if (threadIdx.x < 64){
    int lane = threadIdx.x;
    for (;;){
      int x = (lane<8) ? __hip_atomic_load(f + lane*SHARD, __ATOMIC_ACQUIRE, __HIP_MEMORY_SCOPE_AGENT) : 0;
      x += __shfl_xor(x,1); x += __shfl_xor(x,2); x += __shfl_xor(x,4);
      if (__shfl(x,0) >= target) break;
      __builtin_amdgcn_s_sleep(64);
    }
  }
  __syncthreads();
}

struct SArgs {
  const float *E, *Wx, *Wh, *Wl, *blog;
  float *P, *c2, *h2s, *partA, *glp, *rowamax;
  int *gfin, *glen, *parst, *rowsrc, *cnts;
  void *Lst;
};

// ---- redundant beam select (identical fp32 math in every calling block) ----
// reads: partA(tsel), global state gbuf[(tsel+1)&1]; updates LDS state for ALL
// batches; persists batch myb's slice (myb<0 -> all) to gbuf[tsel&1] + parst/rowamax.
__device__ __forceinline__ void do_select(const SArgs& a, int tsel, int myb,
    float* lblp, int* lprev, int* lpar, int* lfin, int* llen,
    float* sel_lse, float* sel_tv, int* sel_ti)
{
  int tid = threadIdx.x;
  int rid = (tsel+1)&1, wid2 = tsel&1;
  if (tid < NK){
    lblp[tid] = a.glp[rid*128+tid];
    lfin[tid] = a.gfin[rid*128+tid];
    llen[tid] = a.glen[rid*128+tid];
  }
  __syncthreads();
  int wv = tid>>6, lane = tid&63;
  for (int n=wv; n<NK; n+=8){
    float M=FLOORF, S=0.f;
    float tv[3]={FLOORF,FLOORF,FLOORF}; int ti[3]={INTMX,INTMX,INTMX};
    for (int i=lane;i<NLB;i+=64){
      const float* rp = a.partA + ((size_t)n*NLB+i)*8;
      float4 r0=*(const float4*)rp, r1=*((const float4*)rp+1);
      float nm = fmaxf(M,r0.x);
      S = S*expf(M-nm) + r0.y*expf(r0.x-nm);
      M = nm;
      ins3(r0.z,__float_as_int(r1.y),tv,ti);
      ins3(r0.w,__float_as_int(r1.z),tv,ti);
      ins3(r1.x,__float_as_int(r1.w),tv,ti);
    }
    #pragma unroll
    for (int d=1;d<64;d<<=1){
      float Mo=__shfl_xor(M,d), So=__shfl_xor(S,d);
      float nm=fmaxf(M,Mo);
      S = S*expf(M-nm)+So*expf(Mo-nm);
      M=nm;
      float p0=__shfl_xor(tv[0],d),p1=__shfl_xor(tv[1],d),p2=__shfl_xor(tv[2],d);
      int q0=__shfl_xor(ti[0],d),q1=__shfl_xor(ti[1],d),q2=__shfl_xor(ti[2],d);
      ins3(p0,q0,tv,ti); ins3(p1,q1,tv,ti); ins3(p2,q2,tv,ti);
    }
    if (lane==0){
      sel_lse[n] = M + logf(S);
      #pragma unroll
      for (int q=0;q<3;q++){ sel_tv[n*3+q]=tv[q]; sel_ti[n*3+q]=ti[q]; }
      if (myb<0 || n/KW==myb) a.rowamax[tsel*NK+n] = (float)ti[0];
    }
  }
  __syncthreads();
  if (tid < NB){
    int b = tid;
    float cv[3]={FLOORF,FLOORF,FLOORF}; int cf[3]={INTMX,INTMX,INTMX};
    for (int k=0;k<KW;k++){
      int n=b*KW+k;
      if (lfin[n]){
        ins3(lblp[n], k*VV+END_ID, cv,cf);
      } else {
        float blp=lblp[n], lse=sel_lse[n];
        for (int q=0;q<3;q++)
          ins3(blp + (sel_tv[n*3+q]-lse), k*VV+sel_ti[n*3+q], cv,cf);
      }
    }
    int fo[KW], lo[KW];
    for (int q=0;q<KW;q++){ fo[q]=lfin[b*KW+q]; lo[q]=llen[b*KW+q]; }
    for (int kp=0;kp<KW;kp++){
      int par=cf[kp]/VV, word=cf[kp]-par*VV;
      int fp=fo[par];
      int nl = fp?lo[par]:(lo[par]+1);
      int nf = fp | (word==END_ID);
      lblp[b*KW+kp]=cv[kp];
      lprev[b*KW+kp]=word;
      lpar[b*KW+kp]=b*KW+par;
      llen[b*KW+kp]=nl;
      lfin[b*KW+kp]=nf;
      if (myb<0 || b==myb){
        a.parst[tsel*NK + b*KW+kp] = b*KW+par;
        a.glp[wid2*128 + b*KW+kp] = cv[kp];
        a.gfin[wid2*128 + b*KW+kp] = nf;
        a.glen[wid2*128 + b*KW+kp] = nl;
      }
    }
  }
  __syncthreads();
}

// ---------------- P_img = img @ Wx[300:,:] (parts aliases Lst area) ----------------
__global__ __launch_bounds__(128) void k_pimg(const float* __restrict__ img,
                                              const float* __restrict__ Wx,
                                              float* __restrict__ parts)
{
  int colb = blockIdx.x, fb = blockIdx.y, tid = threadIdx.x;
  int col = colb*128 + tid;
  int f0 = fb*128;
  __shared__ float s_img[32][128];
  for (int r=0;r<32;r++) s_img[r][tid] = img[r*FDIM + f0 + tid];
  __syncthreads();
  float acc[32];
  #pragma unroll
  for (int r=0;r<32;r++) acc[r]=0.f;
  for (int f2=0; f2<128; ++f2){
    float w = Wx[(size_t)(DWW + f0 + f2)*G4 + col];
    #pragma unroll
    for (int r=0;r<32;r++) acc[r] += w * s_img[r][f2];
  }
  #pragma unroll
  for (int r=0;r<32;r++) parts[(size_t)fb*(32*G4) + r*G4 + col] = acc[r];
}

// ---------------- prep: P reduce + state init (gbuf[1]) + flag zero + bamax --------
__global__ __launch_bounds__(512) void k_prep(const float* __restrict__ parts,
    const float* __restrict__ bls, const float* __restrict__ blog,
    float* __restrict__ P, float* __restrict__ glp, int* __restrict__ gfin,
    int* __restrict__ glen, int* __restrict__ cnts, float* __restrict__ bamax)
{
  int bid = blockIdx.x, tid = threadIdx.x;
  int gid = bid*512 + tid;
  float s = bls[gid & (G4-1)];
  for (int fb=0; fb<16; ++fb) s += parts[(size_t)fb*(32*G4) + gid];
  P[gid] = s;
  if (gid < TDEC*BAR_STRIDE) cnts[gid] = 0;
  if (bid==0 && tid<NK){
    glp[128+tid] = (tid%KW==0)?0.f:-1e9f;
    gfin[128+tid]=0; glen[128+tid]=0;
  }
  if (bid==2){
    __shared__ float s_rf[8]; __shared__ int s_ri[8];
    float bv=FLOORF; int bi=INTMX;
    for (int i=tid;i<VV;i+=512){
      float v=blog[i];
      if (v>bv || (v==bv && i<bi)){ bv=v; bi=i; }
    }
    #pragma unroll
    for (int d=1;d<64;d<<=1){
      float ov=__shfl_xor(bv,d); int oi=__shfl_xor(bi,d);
      if (ov>bv || (ov==bv && oi<bi)){ bv=ov; bi=oi; }
    }
    if ((tid&63)==0){ s_rf[tid>>6]=bv; s_ri[tid>>6]=bi; }
    __syncthreads();
    if (tid==0){
      for (int w=1;w<8;w++)
        if (s_rf[w]>bv || (s_rf[w]==bv && s_ri[w]<bi)){ bv=s_rf[w]; bi=s_ri[w]; }
      bamax[0] = (float)bi;
    }
  }
}

// ---------------- k_step: one launch per decode step ------------------------------
// blocks 0..31:  select(t-1) redundant -> fused Z+gates (cols {j*16+mm+q*512}) -> arrive
// blocks 32..219: prefetch Wl slice to LDS -> wait -> logits GEMM + records + Lst
template<int BF, int WLDS>
__global__ __launch_bounds__(512,1) void k_step(SArgs a, int t)
{
  extern __shared__ float dsm[];
  const int bid = blockIdx.x, tid = threadIdx.x;
  int* bG = a.cnts + (size_t)t*BAR_STRIDE;

  if (bid < NZB){
    const int j = bid;
    float* sA   = dsm;                       // 96*65 (zl aliases: 96*64)
    float* sB   = sA + 96*65;                // 64*64
    float* lblp = sB + 64*64;                // 96
    float* sel_lse = lblp + 96;              // 96
    float* sel_tv  = sel_lse + 96;           // 288
    int*   sel_ti  = (int*)(sel_tv + 288);   // 288
    int*   lprev   = sel_ti + 288;           // 96
    int*   lpar    = lprev + 96;             // 96
    int*   lfin    = lpar + 96;              // 96
    int*   llen    = lfin + 96;              // 96

    if (t==0){
      if (tid<NK){ lprev[tid]=START_ID; lpar[tid]=0; }
      __syncthreads();
    } else {
      do_select(a, t-1, j, lblp,lprev,lpar,lfin,llen, sel_lse,sel_tv,sel_ti);
    }

    // ---- fused Z: z[96][{j*16+mm+q*512}] full K=812 ----
    const int tx = tid&15, ty = tid>>4;
    float4 acc[3];
    #pragma unroll
    for (int r=0;r<3;r++) acc[r]=make_float4(0.f,0.f,0.f,0.f);
    for (int k0=0;k0<812;k0+=64){
      int bk = 812-k0; if (bk>64) bk=64;
      for (int i=tid;i<96*64;i+=512){
        int n=i>>6, kk=i&63;
        float v=0.f;
        if (kk<bk){
          int kg=k0+kk;
          if (kg<DWW) v = a.E[(size_t)lprev[n]*DWW+kg];
          else if (t>0) v = a.h2s[((size_t)(t-1)*NK + lpar[n])*HH + (kg-DWW)];
        }
        sA[n*65+kk]=v;
      }
      for (int i=tid;i<64*64;i+=512){
        int kk=i>>6, cc=i&63;
        float v=0.f;
        if (kk<bk){
          int kg=k0+kk;
          int colg = j*16 + (cc&15) + (cc>>4)*512;
          v = (kg<DWW) ? a.Wx[(size_t)kg*G4+colg] : a.Wh[(size_t)(kg-DWW)*G4+colg];
        }
        sB[i]=v;
      }
      __syncthreads();
      #pragma unroll 8
      for (int kk=0;kk<64;++kk){
        float4 b4 = *(const float4*)&sB[kk*64+tx*4];
        #pragma unroll
        for (int rr=0;rr<3;rr++){
          float av = sA[(ty+rr*32)*65+kk];
          acc[rr].x += av*b4.x; acc[rr].y += av*b4.y;
          acc[rr].z += av*b4.z; acc[rr].w += av*b4.w;
        }
      }
      __syncthreads();
    }
    float* zl = sA;   // alias, safe after trailing sync
    #pragma unroll
    for (int rr=0;rr<3;rr++)
      *(float4*)&zl[(ty+rr*32)*64 + tx*4] = acc[rr];
    __syncthreads();

    // ---- gates for m = j*16..j*16+15, all 96 rows ----
    for (int oi=tid; oi<NK*16; oi+=512){
      int n=oi>>4, mm=oi&15;
      int m=j*16+mm;
      const float* Pr = a.P + (size_t)(n/KW)*G4;
      float zi = zl[n*64     +mm] + Pr[m];
      float zf = zl[n*64+16  +mm] + Pr[HH+m];
      float zg = zl[n*64+32  +mm] + Pr[2*HH+m];
      float zo = zl[n*64+48  +mm] + Pr[3*HH+m];
      float cold = (t==0) ? 0.f : a.c2[(size_t)((t-1)&1)*NK*HH + (size_t)lpar[n]*HH + m];
      float c2v = sigf(zf+1.0f)*cold + sigf(zi)*tanhf(zg);
      float h2v = sigf(zo)*tanhf(c2v);
      a.c2[(size_t)(t&1)*NK*HH + (size_t)n*HH + m] = c2v;
      a.h2s[((size_t)t*NK+n)*HH + m] = h2v;
    }
    __syncthreads();
    if (tid==0) flag_arrive(bG, bid);
    return;
  }

  // ---------------- logits blocks ----------------
  const int lblk = bid - NZB;
  const int col0 = lblk*64;
  float* Wl_lds = dsm;                          // 512*64 (WLDS=1)
  float* sAl = WLDS ? (dsm + 512*64) : dsm;     // 96*36
  float* sBl = WLDS ? (float*)0 : (sAl + 96*36);// 32*64 (WLDS=0)

  if (WLDS){
    // prefetch Wl slice while producers run (useful work instead of polling)
    for (int i=tid;i<512*16;i+=512){
      int kk=i>>4, c4=(i&15)*4, col=col0+c4;
      float4 v = make_float4(0.f,0.f,0.f,0.f);
      if (col < VV) v = *(const float4*)&a.Wl[(size_t)kk*VV+col];
      *(float4*)&Wl_lds[kk*64+c4] = v;
    }
  }
  flag_wait(bG, NZB);   // trailing __syncthreads also covers Wl_lds visibility

  const int tx=tid&15, ty=tid>>4;
  float4 acc[3];
  #pragma unroll
  for (int r=0;r<3;r++) acc[r]=make_float4(0.f,0.f,0.f,0.f);
  for (int k0=0;k0<HH;k0+=32){
    for (int i=tid;i<768;i+=512){
      int row=i>>3, kq=(i&7)*4;
      *(float4*)&sAl[row*36+kq] = *(const float4*)&a.h2s[((size_t)t*NK+row)*HH + k0+kq];
    }
    if (!WLDS){
      int kk=tid>>4, c4=(tid&15)*4;
      int col=col0+c4;
      float4 v = make_float4(0.f,0.f,0.f,0.f);
      if (col < VV) v = *(const float4*)&a.Wl[(size_t)(k0+kk)*VV+col];
      *(float4*)&sBl[kk*64+c4]=v;
    }
    __syncthreads();
    #pragma unroll
    for (int kk=0;kk<32;++kk){
      float4 b4 = WLDS ? *(const float4*)&Wl_lds[(k0+kk)*64+tx*4]
                       : *(const float4*)&sBl[kk*64+tx*4];
      #pragma unroll
      for (int rr=0;rr<3;rr++){
        float av = sAl[(ty+rr*32)*36+kk];
        acc[rr].x += av*b4.x; acc[rr].y += av*b4.y;
        acc[rr].z += av*b4.z; acc[rr].w += av*b4.w;
      }
    }
    __syncthreads();
  }
  int colg = col0 + tx*4;
  bool cval = colg < VV;
  float4 bias = make_float4(0.f,0.f,0.f,0.f);
  if (cval) bias = *(const float4*)&a.blog[colg];
  #pragma unroll
  for (int rr=0;rr<3;rr++){
    int row = ty + rr*32;
    float v0,v1,v2,v3;
    if (cval){
      v0=acc[rr].x+bias.x; v1=acc[rr].y+bias.y;
      v2=acc[rr].z+bias.z; v3=acc[rr].w+bias.w;
      size_t off = (size_t)(t*NK+row)*VV + colg;
      if (BF){
        ushort4 u;
        u.x=f2b(v0); u.y=f2b(v1); u.z=f2b(v2); u.w=f2b(v3);
        *(ushort4*)((unsigned short*)a.Lst + off) = u;
      } else {
        nt_store4((float*)a.Lst + off, make_float4(v0,v1,v2,v3));
      }
    } else { v0=v1=v2=v3=-INFINITY; }
    float m = fmaxf(fmaxf(v0,v1),fmaxf(v2,v3));
    #pragma unroll
    for (int d=1;d<16;d<<=1) m = fmaxf(m,__shfl_xor(m,d));
    float tv[3]={-INFINITY,-INFINITY,-INFINITY};
    int   ti[3]={INTMX,INTMX,INTMX};
    float s=0.f;
    if (cval){
      ins3(v0,colg,tv,ti); ins3(v1,colg+1,tv,ti);
      ins3(v2,colg+2,tv,ti); ins3(v3,colg+3,tv,ti);
      s = expf(v0-m)+expf(v1-m)+expf(v2-m)+expf(v3-m);
    }
    #pragma unroll
    for (int d=1;d<16;d<<=1){
      s += __shfl_xor(s,d);
      float p0=__shfl_xor(tv[0],d),p1=__shfl_xor(tv[1],d),p2=__shfl_xor(tv[2],d);
      int q0=__shfl_xor(ti[0],d),q1=__shfl_xor(ti[1],d),q2=__shfl_xor(ti[2],d);
      ins3(p0,q0,tv,ti); ins3(p1,q1,tv,ti); ins3(p2,q2,tv,ti);
    }
    if (tx==0){
      float* rp = a.partA + ((size_t)row*NLB + lblk)*8;
      *(float4*)rp = make_float4(m,s,tv[0],tv[1]);
      *((float4*)rp+1) = make_float4(tv[2],__int_as_float(ti[0]),__int_as_float(ti[1]),__int_as_float(ti[2]));
    }
  }
}

// ---------------- final select + backtrack (single block) ----------------
__global__ __launch_bounds__(512) void k_fin(SArgs a)
{
  __shared__ float lblp[NK], sel_lse[NK], sel_tv[NK*3];
  __shared__ int   sel_ti[NK*3], lprev[NK], lpar[NK], lfin[NK], llen[NK];
  do_select(a, TDEC-1, -1, lblp,lprev,lpar,lfin,llen, sel_lse,sel_tv,sel_ti);
  int tid = threadIdx.x;
  if (tid < NK){
    int n=tid, b=n/KW;
    int len = llen[n];
    a.rowsrc[n*SEQ+TDEC] = -1;
    int cur=n;
    for (int tau=TDEC-1; tau>=1; --tau){
      int p = a.parst[tau*NK+cur];
      a.rowsrc[n*SEQ+tau] = (tau<len) ? (tau*NK+p) : -1;
      cur=p;
    }
    a.rowsrc[n*SEQ+0] = b*KW;
  }
}

// ---------------- gather: out rows from stored decode logits ----------------
template<int BF>
__global__ __launch_bounds__(512) void k_gather(const void* __restrict__ Lst,
    const int* __restrict__ rowsrc, const float* __restrict__ rowamax,
    const float* __restrict__ bamax, const float* __restrict__ blog,
    float* __restrict__ out)
{
  int row = blockIdx.x, tid = threadIdx.x;
  int src = rowsrc[row];
  float* orow = out + (size_t)row*VV;
  if (src >= 0){
    if (BF){
      const unsigned short* L = (const unsigned short*)Lst + (size_t)src*VV;
      for (int j=tid;j<VV/4;j+=512){
        ushort4 u = *(const ushort4*)&L[j*4];
        float4 v;
        v.x = __uint_as_float(((unsigned)u.x)<<16);
        v.y = __uint_as_float(((unsigned)u.y)<<16);
        v.z = __uint_as_float(((unsigned)u.z)<<16);
        v.w = __uint_as_float(((unsigned)u.w)<<16);
        nt_store4(&orow[j*4], v);
      }
    } else {
      const float* L = (const float*)Lst + (size_t)src*VV;
      for (int j=tid;j<VV/4;j+=512){
        float4 v = *(const float4*)&L[j*4];
        nt_store4(&orow[j*4], v);
      }
    }
    if (tid==0) out[(size_t)NROWS*VV + row] = rowamax[src];
  } else {
    for (int j=tid;j<VV/4;j+=512){
      float4 v = *(const float4*)&blog[j*4];
      nt_store4(&orow[j*4], v);
    }
    if (tid==0) out[(size_t)NROWS*VV + row] = bamax[0];
  }
}

extern "C" void kernel_launch(void* const* d_in, const int* in_sizes, int n_in,
                              void* d_out, int out_size, void* d_ws, size_t ws_size,
                              hipStream_t stream) {
  (void)in_sizes; (void)n_in; (void)out_size;
  const float* img  = (const float*)d_in[0];
  const float* E    = (const float*)d_in[1];
  const float* Wx   = (const float*)d_in[2];
  const float* Wh   = (const float*)d_in[3];
  const float* bls  = (const float*)d_in[4];
  const float* Wl   = (const float*)d_in[5];
  const float* blog = (const float*)d_in[6];
  float* out = (float*)d_out;

  float* ws = (float*)d_ws;
  size_t o = 0;
  float* P       = ws+o; o += (size_t)NB*G4;         // 65536
  float* c2      = ws+o; o += (size_t)2*NK*HH;       // double buffer
  float* h2s     = ws+o; o += (size_t)TDEC*NK*HH;    // per-step h2
  float* partA   = ws+o; o += (size_t)NK*NLB*8;
  float* glp     = ws+o; o += 256;                   // beam_lp double buffer
  float* rowamax = ws+o; o += (size_t)TDEC*NK;
  float* bamax   = ws+o; o += 4;
  int* gfin      = (int*)(ws+o); o += 256;
  int* glen      = (int*)(ws+o); o += 256;
  int* parst     = (int*)(ws+o); o += (size_t)TDEC*NK;
  int* rowsrc    = (int*)(ws+o); o += 3328;
  int* cnts      = (int*)(ws+o); o += (size_t)TDEC*BAR_STRIDE;  // 16384
  o = (o+3) & ~(size_t)3;
  void* Lst      = (void*)(ws+o);
  float* parts   = (float*)Lst;   // pimg scratch aliases Lst (consumed by prep first)

  bool f32 = (ws_size/4 > o) && ((ws_size/4 - o) >= (size_t)TDEC*NK*VV);

  SArgs a;
  a.E=E; a.Wx=Wx; a.Wh=Wh; a.Wl=Wl; a.blog=blog;
  a.P=P; a.c2=c2; a.h2s=h2s; a.partA=partA; a.glp=glp; a.rowamax=rowamax;
  a.gfin=gfin; a.glen=glen; a.parst=parst; a.rowsrc=rowsrc; a.cnts=cnts;
  a.Lst=Lst;

  const int DSMB_BIG = (512*64 + 96*36)*4;   // 144896 B (logits); Z path uses 45952
  const int DSMB_SML = (96*65 + 64*64 + 96 + 96 + 288 + 288 + 96*4)*4;  // 45952 B

  k_pimg<<<dim3(16,16),128,0,stream>>>(img, Wx, parts);
  k_prep<<<128,512,0,stream>>>(parts, bls, blog, P, glp, gfin, glen, cnts, bamax);

  if (f32){
    bool big = hipFuncSetAttribute((const void*)k_step<0,1>,
          hipFuncAttributeMaxDynamicSharedMemorySize, DSMB_BIG) == hipSuccess;
    for (int t=0;t<TDEC;t++){
      if (big) k_step<0,1><<<GRID,512,(unsigned)DSMB_BIG,stream>>>(a,t);
      else     k_step<0,0><<<GRID,512,(unsigned)DSMB_SML,stream>>>(a,t);
    }
    k_fin<<<1,512,0,stream>>>(a);
    k_gather<0><<<NROWS,512,0,stream>>>(Lst,rowsrc,rowamax,bamax,blog,out);
  } else {
    bool big = hipFuncSetAttribute((const void*)k_step<1,1>,
          hipFuncAttributeMaxDynamicSharedMemorySize, DSMB_BIG) == hipSuccess;
    for (int t=0;t<TDEC;t++){
      if (big) k_step<1,1><<<GRID,512,(unsigned)DSMB_BIG,stream>>>(a,t);
      else     k_step<1,0><<<GRID,512,(unsigned)DSMB_SML,stream>>>(a,t);
    }
    k_fin<<<1,512,0,stream>>>(a);
    k_gather<1><<<NROWS,512,0,stream>>>(Lst,rowsrc,rowamax,bamax,blog,out);
  }
}

// Round 10
// 7764.845 us; speedup vs baseline: 1.3159x; 1.3159x over previous
//
#include <hip/hip_runtime.h>
#include <hip/hip_bf16.h>
#include <math.h>

#define NB   32
#define FDIM 2048
#define VV   12000
#define DWW  300
#define HH   512
#define KW   3
#define TDEC 32
#define SEQ  33
#define NK   96
#define G4   2048
#define START_ID 1
#define END_ID   2
#define NROWS 3168
#define NZB  32      // fused select+Z+gates blocks
#define NLB  188     // logits blocks (64 cols each)
#define INTMX 0x7fffffff
#define FLOORF (-3.0e38f)

typedef float f4v __attribute__((ext_vector_type(4)));
__device__ __forceinline__ void nt_store4(float* p, float4 v){
  f4v t; t.x=v.x; t.y=v.y; t.z=v.z; t.w=v.w;
  __builtin_nontemporal_store(t, (f4v*)p);
}

__device__ __forceinline__ float sigf(float x){ return 1.0f/(1.0f+expf(-x)); }

__device__ __forceinline__ unsigned short f2b(float x){
  __hip_bfloat16 b = __float2bfloat16(x);
  return *reinterpret_cast<unsigned short*>(&b);
}

// insert (v,i) into sorted-desc top3; tie -> smaller index wins
__device__ __forceinline__ void ins3(float v, int i, float tv[3], int ti[3]){
  if (v > tv[0] || (v == tv[0] && i < ti[0])){
    tv[2]=tv[1]; ti[2]=ti[1]; tv[1]=tv[0]; ti[1]=ti[0]; tv[0]=v; ti[0]=i;
  } else if (v > tv[1] || (v == tv[1] && i < ti[1])){
    tv[2]=tv[1]; ti[2]=ti[1]; tv[1]=v; ti[1]=i;
  } else if (v > tv[2] || (v == tv[2] && i < ti[2])){
    tv[2]=v; ti[2]=i;
  }
}

struct SArgs {
  const float *E, *Wx, *Wh, *Wl, *blog;
  float *P, *c2, *h2s, *partA, *glp, *rowamax;
  int *gfin, *glen, *parst, *rowsrc;
  void *Lst;
};

// ---- redundant beam select (identical fp32 math in every calling block) ----
// reads: partA(tsel), global state gbuf[(tsel+1)&1]; updates LDS state for ALL
// batches; persists batch myb's slice (myb<0 -> all) to gbuf[tsel&1] + parst/rowamax.
__device__ __forceinline__ void do_select(const SArgs& a, int tsel, int myb,
    float* lblp, int* lprev, int* lpar, int* lfin, int* llen,
    float* sel_lse, float* sel_tv, int* sel_ti)
{
  int tid = threadIdx.x;
  int rid = (tsel+1)&1, wid2 = tsel&1;
  if (tid < NK){
    lblp[tid] = a.glp[rid*128+tid];
    lfin[tid] = a.gfin[rid*128+tid];
    llen[tid] = a.glen[rid*128+tid];
  }
  __syncthreads();
  int wv = tid>>6, lane = tid&63;
  for (int n=wv; n<NK; n+=8){
    float M=FLOORF, S=0.f;
    float tv[3]={FLOORF,FLOORF,FLOORF}; int ti[3]={INTMX,INTMX,INTMX};
    for (int i=lane;i<NLB;i+=64){
      const float* rp = a.partA + ((size_t)n*NLB+i)*8;
      float4 r0=*(const float4*)rp, r1=*((const float4*)rp+1);
      float nm = fmaxf(M,r0.x);
      S = S*expf(M-nm) + r0.y*expf(r0.x-nm);
      M = nm;
      ins3(r0.z,__float_as_int(r1.y),tv,ti);
      ins3(r0.w,__float_as_int(r1.z),tv,ti);
      ins3(r1.x,__float_as_int(r1.w),tv,ti);
    }
    #pragma unroll
    for (int d=1;d<64;d<<=1){
      float Mo=__shfl_xor(M,d), So=__shfl_xor(S,d);
      float nm=fmaxf(M,Mo);
      S = S*expf(M-nm)+So*expf(Mo-nm);
      M=nm;
      float p0=__shfl_xor(tv[0],d),p1=__shfl_xor(tv[1],d),p2=__shfl_xor(tv[2],d);
      int q0=__shfl_xor(ti[0],d),q1=__shfl_xor(ti[1],d),q2=__shfl_xor(ti[2],d);
      ins3(p0,q0,tv,ti); ins3(p1,q1,tv,ti); ins3(p2,q2,tv,ti);
    }
    if (lane==0){
      sel_lse[n] = M + logf(S);
      #pragma unroll
      for (int q=0;q<3;q++){ sel_tv[n*3+q]=tv[q]; sel_ti[n*3+q]=ti[q]; }
      if (myb<0 || n/KW==myb) a.rowamax[tsel*NK+n] = (float)ti[0];
    }
  }
  __syncthreads();
  if (tid < NB){
    int b = tid;
    float cv[3]={FLOORF,FLOORF,FLOORF}; int cf[3]={INTMX,INTMX,INTMX};
    for (int k=0;k<KW;k++){
      int n=b*KW+k;
      if (lfin[n]){
        ins3(lblp[n], k*VV+END_ID, cv,cf);
      } else {
        float blp=lblp[n], lse=sel_lse[n];
        for (int q=0;q<3;q++)
          ins3(blp + (sel_tv[n*3+q]-lse), k*VV+sel_ti[n*3+q], cv,cf);
      }
    }
    int fo[KW], lo[KW];
    for (int q=0;q<KW;q++){ fo[q]=lfin[b*KW+q]; lo[q]=llen[b*KW+q]; }
    for (int kp=0;kp<KW;kp++){
      int par=cf[kp]/VV, word=cf[kp]-par*VV;
      int fp=fo[par];
      int nl = fp?lo[par]:(lo[par]+1);
      int nf = fp | (word==END_ID);
      lblp[b*KW+kp]=cv[kp];
      lprev[b*KW+kp]=word;
      lpar[b*KW+kp]=b*KW+par;
      llen[b*KW+kp]=nl;
      lfin[b*KW+kp]=nf;
      if (myb<0 || b==myb){
        a.parst[tsel*NK + b*KW+kp] = b*KW+par;
        a.glp[wid2*128 + b*KW+kp] = cv[kp];
        a.gfin[wid2*128 + b*KW+kp] = nf;
        a.glen[wid2*128 + b*KW+kp] = nl;
      }
    }
  }
  __syncthreads();
}

// ---------------- P_img = img @ Wx[300:,:] (parts aliases Lst area) ----------------
__global__ __launch_bounds__(128) void k_pimg(const float* __restrict__ img,
                                              const float* __restrict__ Wx,
                                              float* __restrict__ parts)
{
  int colb = blockIdx.x, fb = blockIdx.y, tid = threadIdx.x;
  int col = colb*128 + tid;
  int f0 = fb*128;
  __shared__ float s_img[32][128];
  for (int r=0;r<32;r++) s_img[r][tid] = img[r*FDIM + f0 + tid];
  __syncthreads();
  float acc[32];
  #pragma unroll
  for (int r=0;r<32;r++) acc[r]=0.f;
  for (int f2=0; f2<128; ++f2){
    float w = Wx[(size_t)(DWW + f0 + f2)*G4 + col];
    #pragma unroll
    for (int r=0;r<32;r++) acc[r] += w * s_img[r][f2];
  }
  #pragma unroll
  for (int r=0;r<32;r++) parts[(size_t)fb*(32*G4) + r*G4 + col] = acc[r];
}

// ---------------- prep: P reduce + state init (gbuf[1]) + bamax ----------------
__global__ __launch_bounds__(512) void k_prep(const float* __restrict__ parts,
    const float* __restrict__ bls, const float* __restrict__ blog,
    float* __restrict__ P, float* __restrict__ glp, int* __restrict__ gfin,
    int* __restrict__ glen, float* __restrict__ bamax)
{
  int bid = blockIdx.x, tid = threadIdx.x;
  int gid = bid*512 + tid;
  float s = bls[gid & (G4-1)];
  for (int fb=0; fb<16; ++fb) s += parts[(size_t)fb*(32*G4) + gid];
  P[gid] = s;
  if (bid==0 && tid<NK){
    glp[128+tid] = (tid%KW==0)?0.f:-1e9f;
    gfin[128+tid]=0; glen[128+tid]=0;
  }
  if (bid==2){
    __shared__ float s_rf[8]; __shared__ int s_ri[8];
    float bv=FLOORF; int bi=INTMX;
    for (int i=tid;i<VV;i+=512){
      float v=blog[i];
      if (v>bv || (v==bv && i<bi)){ bv=v; bi=i; }
    }
    #pragma unroll
    for (int d=1;d<64;d<<=1){
      float ov=__shfl_xor(bv,d); int oi=__shfl_xor(bi,d);
      if (ov>bv || (ov==bv && oi<bi)){ bv=ov; bi=oi; }
    }
    if ((tid&63)==0){ s_rf[tid>>6]=bv; s_ri[tid>>6]=bi; }
    __syncthreads();
    if (tid==0){
      for (int w=1;w<8;w++)
        if (s_rf[w]>bv || (s_rf[w]==bv && s_ri[w]<bi)){ bv=s_rf[w]; bi=s_ri[w]; }
      bamax[0] = (float)bi;
    }
  }
}

// ---------------- k_stepA: select(t-1) + fused Z + gates (32 blocks, no sync) ------
__global__ __launch_bounds__(512,1) void k_stepA(SArgs a, int t)
{
  __shared__ float sA[96*65];      // staging; aliased as zl[96][64] after GEMM
  __shared__ float sB[64*64];
  __shared__ float lblp[NK], sel_lse[NK], sel_tv[NK*3];
  __shared__ int   sel_ti[NK*3], lprev[NK], lpar[NK], lfin[NK], llen[NK];
  const int j = blockIdx.x, tid = threadIdx.x;

  if (t==0){
    if (tid<NK){ lprev[tid]=START_ID; lpar[tid]=0; }
    __syncthreads();
  } else {
    do_select(a, t-1, j, lblp,lprev,lpar,lfin,llen, sel_lse,sel_tv,sel_ti);
  }

  // ---- fused Z: z[96][{j*16+mm+q*512}] full K=812 ----
  const int tx = tid&15, ty = tid>>4;
  float4 acc[3];
  #pragma unroll
  for (int r=0;r<3;r++) acc[r]=make_float4(0.f,0.f,0.f,0.f);
  for (int k0=0;k0<812;k0+=64){
    int bk = 812-k0; if (bk>64) bk=64;
    for (int i=tid;i<96*64;i+=512){
      int n=i>>6, kk=i&63;
      float v=0.f;
      if (kk<bk){
        int kg=k0+kk;
        if (kg<DWW) v = a.E[(size_t)lprev[n]*DWW+kg];
        else if (t>0) v = a.h2s[((size_t)(t-1)*NK + lpar[n])*HH + (kg-DWW)];
      }
      sA[n*65+kk]=v;
    }
    for (int i=tid;i<64*64;i+=512){
      int kk=i>>6, cc=i&63;
      float v=0.f;
      if (kk<bk){
        int kg=k0+kk;
        int colg = j*16 + (cc&15) + (cc>>4)*512;
        v = (kg<DWW) ? a.Wx[(size_t)kg*G4+colg] : a.Wh[(size_t)(kg-DWW)*G4+colg];
      }
      sB[i]=v;
    }
    __syncthreads();
    #pragma unroll 8
    for (int kk=0;kk<64;++kk){
      float4 b4 = *(const float4*)&sB[kk*64+tx*4];
      #pragma unroll
      for (int rr=0;rr<3;rr++){
        float av = sA[(ty+rr*32)*65+kk];
        acc[rr].x += av*b4.x; acc[rr].y += av*b4.y;
        acc[rr].z += av*b4.z; acc[rr].w += av*b4.w;
      }
    }
    __syncthreads();
  }
  float* zl = sA;   // alias, safe after trailing sync
  #pragma unroll
  for (int rr=0;rr<3;rr++)
    *(float4*)&zl[(ty+rr*32)*64 + tx*4] = acc[rr];
  __syncthreads();

  // ---- gates for m = j*16..j*16+15, all 96 rows ----
  for (int oi=tid; oi<NK*16; oi+=512){
    int n=oi>>4, mm=oi&15;
    int m=j*16+mm;
    const float* Pr = a.P + (size_t)(n/KW)*G4;
    float zi = zl[n*64     +mm] + Pr[m];
    float zf = zl[n*64+16  +mm] + Pr[HH+m];
    float zg = zl[n*64+32  +mm] + Pr[2*HH+m];
    float zo = zl[n*64+48  +mm] + Pr[3*HH+m];
    float cold = (t==0) ? 0.f : a.c2[(size_t)((t-1)&1)*NK*HH + (size_t)lpar[n]*HH + m];
    float c2v = sigf(zf+1.0f)*cold + sigf(zi)*tanhf(zg);
    float h2v = sigf(zo)*tanhf(c2v);
    a.c2[(size_t)(t&1)*NK*HH + (size_t)n*HH + m] = c2v;
    a.h2s[((size_t)t*NK+n)*HH + m] = h2v;
  }
}

// ---------------- k_stepB: logits GEMM + records + Lst (188 blocks, no sync) -------
template<int BF>
__global__ __launch_bounds__(512) void k_stepB(SArgs a, int t)
{
  __shared__ float smem[96*36 + 32*64];
  const int bid = blockIdx.x, tid = threadIdx.x;
  const int col0 = bid*64;
  float* sAl = smem;
  float* sBl = smem + 96*36;
  const int tx=tid&15, ty=tid>>4;
  float4 acc[3];
  #pragma unroll
  for (int r=0;r<3;r++) acc[r]=make_float4(0.f,0.f,0.f,0.f);
  for (int k0=0;k0<HH;k0+=32){
    for (int i=tid;i<768;i+=512){
      int row=i>>3, kq=(i&7)*4;
      *(float4*)&sAl[row*36+kq] = *(const float4*)&a.h2s[((size_t)t*NK+row)*HH + k0+kq];
    }
    {
      int kk=tid>>4, c4=(tid&15)*4;
      int col=col0+c4;
      float4 v = make_float4(0.f,0.f,0.f,0.f);
      if (col < VV) v = *(const float4*)&a.Wl[(size_t)(k0+kk)*VV+col];
      *(float4*)&sBl[kk*64+c4]=v;
    }
    __syncthreads();
    #pragma unroll
    for (int kk=0;kk<32;++kk){
      float4 b4 = *(const float4*)&sBl[kk*64+tx*4];
      #pragma unroll
      for (int rr=0;rr<3;rr++){
        float av = sAl[(ty+rr*32)*36+kk];
        acc[rr].x += av*b4.x; acc[rr].y += av*b4.y;
        acc[rr].z += av*b4.z; acc[rr].w += av*b4.w;
      }
    }
    __syncthreads();
  }
  int colg = col0 + tx*4;
  bool cval = colg < VV;
  float4 bias = make_float4(0.f,0.f,0.f,0.f);
  if (cval) bias = *(const float4*)&a.blog[colg];
  #pragma unroll
  for (int rr=0;rr<3;rr++){
    int row = ty + rr*32;
    float v0,v1,v2,v3;
    if (cval){
      v0=acc[rr].x+bias.x; v1=acc[rr].y+bias.y;
      v2=acc[rr].z+bias.z; v3=acc[rr].w+bias.w;
      size_t off = (size_t)(t*NK+row)*VV + colg;
      if (BF){
        ushort4 u;
        u.x=f2b(v0); u.y=f2b(v1); u.z=f2b(v2); u.w=f2b(v3);
        *(ushort4*)((unsigned short*)a.Lst + off) = u;
      } else {
        nt_store4((float*)a.Lst + off, make_float4(v0,v1,v2,v3));
      }
    } else { v0=v1=v2=v3=-INFINITY; }
    float m = fmaxf(fmaxf(v0,v1),fmaxf(v2,v3));
    #pragma unroll
    for (int d=1;d<16;d<<=1) m = fmaxf(m,__shfl_xor(m,d));
    float tv[3]={-INFINITY,-INFINITY,-INFINITY};
    int   ti[3]={INTMX,INTMX,INTMX};
    float s=0.f;
    if (cval){
      ins3(v0,colg,tv,ti); ins3(v1,colg+1,tv,ti);
      ins3(v2,colg+2,tv,ti); ins3(v3,colg+3,tv,ti);
      s = expf(v0-m)+expf(v1-m)+expf(v2-m)+expf(v3-m);
    }
    #pragma unroll
    for (int d=1;d<16;d<<=1){
      s += __shfl_xor(s,d);
      float p0=__shfl_xor(tv[0],d),p1=__shfl_xor(tv[1],d),p2=__shfl_xor(tv[2],d);
      int q0=__shfl_xor(ti[0],d),q1=__shfl_xor(ti[1],d),q2=__shfl_xor(ti[2],d);
      ins3(p0,q0,tv,ti); ins3(p1,q1,tv,ti); ins3(p2,q2,tv,ti);
    }
    if (tx==0){
      float* rp = a.partA + ((size_t)row*NLB + bid)*8;
      *(float4*)rp = make_float4(m,s,tv[0],tv[1]);
      *((float4*)rp+1) = make_float4(tv[2],__int_as_float(ti[0]),__int_as_float(ti[1]),__int_as_float(ti[2]));
    }
  }
}

// ---------------- final select + backtrack (single block) ----------------
__global__ __launch_bounds__(512) void k_fin(SArgs a)
{
  __shared__ float lblp[NK], sel_lse[NK], sel_tv[NK*3];
  __shared__ int   sel_ti[NK*3], lprev[NK], lpar[NK], lfin[NK], llen[NK];
  do_select(a, TDEC-1, -1, lblp,lprev,lpar,lfin,llen, sel_lse,sel_tv,sel_ti);
  int tid = threadIdx.x;
  if (tid < NK){
    int n=tid, b=n/KW;
    int len = llen[n];
    a.rowsrc[n*SEQ+TDEC] = -1;
    int cur=n;
    for (int tau=TDEC-1; tau>=1; --tau){
      int p = a.parst[tau*NK+cur];
      a.rowsrc[n*SEQ+tau] = (tau<len) ? (tau*NK+p) : -1;
      cur=p;
    }
    a.rowsrc[n*SEQ+0] = b*KW;
  }
}

// ---------------- gather: out rows from stored decode logits ----------------
template<int BF>
__global__ __launch_bounds__(512) void k_gather(const void* __restrict__ Lst,
    const int* __restrict__ rowsrc, const float* __restrict__ rowamax,
    const float* __restrict__ bamax, const float* __restrict__ blog,
    float* __restrict__ out)
{
  int row = blockIdx.x, tid = threadIdx.x;
  int src = rowsrc[row];
  float* orow = out + (size_t)row*VV;
  if (src >= 0){
    if (BF){
      const unsigned short* L = (const unsigned short*)Lst + (size_t)src*VV;
      for (int j=tid;j<VV/4;j+=512){
        ushort4 u = *(const ushort4*)&L[j*4];
        float4 v;
        v.x = __uint_as_float(((unsigned)u.x)<<16);
        v.y = __uint_as_float(((unsigned)u.y)<<16);
        v.z = __uint_as_float(((unsigned)u.z)<<16);
        v.w = __uint_as_float(((unsigned)u.w)<<16);
        nt_store4(&orow[j*4], v);
      }
    } else {
      const float* L = (const float*)Lst + (size_t)src*VV;
      for (int j=tid;j<VV/4;j+=512){
        float4 v = *(const float4*)&L[j*4];
        nt_store4(&orow[j*4], v);
      }
    }
    if (tid==0) out[(size_t)NROWS*VV + row] = rowamax[src];
  } else {
    for (int j=tid;j<VV/4;j+=512){
      float4 v = *(const float4*)&blog[j*4];
      nt_store4(&orow[j*4], v);
    }
    if (tid==0) out[(size_t)NROWS*VV + row] = bamax[0];
  }
}

extern "C" void kernel_launch(void* const* d_in, const int* in_sizes, int n_in,
                              void* d_out, int out_size, void* d_ws, size_t ws_size,
                              hipStream_t stream) {
  (void)in_sizes; (void)n_in; (void)out_size;
  const float* img  = (const float*)d_in[0];
  const float* E    = (const float*)d_in[1];
  const float* Wx   = (const float*)d_in[2];
  const float* Wh   = (const float*)d_in[3];
  const float* bls  = (const float*)d_in[4];
  const float* Wl   = (const float*)d_in[5];
  const float* blog = (const float*)d_in[6];
  float* out = (float*)d_out;

  float* ws = (float*)d_ws;
  size_t o = 0;
  float* P       = ws+o; o += (size_t)NB*G4;         // 65536
  float* c2      = ws+o; o += (size_t)2*NK*HH;       // double buffer
  float* h2s     = ws+o; o += (size_t)TDEC*NK*HH;    // per-step h2
  float* partA   = ws+o; o += (size_t)NK*NLB*8;
  float* glp     = ws+o; o += 256;                   // beam_lp double buffer
  float* rowamax = ws+o; o += (size_t)TDEC*NK;
  float* bamax   = ws+o; o += 4;
  int* gfin      = (int*)(ws+o); o += 256;
  int* glen      = (int*)(ws+o); o += 256;
  int* parst     = (int*)(ws+o); o += (size_t)TDEC*NK;
  int* rowsrc    = (int*)(ws+o); o += 3328;
  o = (o+3) & ~(size_t)3;
  void* Lst      = (void*)(ws+o);
  float* parts   = (float*)Lst;   // pimg scratch aliases Lst (consumed by prep first)

  bool f32 = (ws_size/4 > o) && ((ws_size/4 - o) >= (size_t)TDEC*NK*VV);

  SArgs a;
  a.E=E; a.Wx=Wx; a.Wh=Wh; a.Wl=Wl; a.blog=blog;
  a.P=P; a.c2=c2; a.h2s=h2s; a.partA=partA; a.glp=glp; a.rowamax=rowamax;
  a.gfin=gfin; a.glen=glen; a.parst=parst; a.rowsrc=rowsrc;
  a.Lst=Lst;

  k_pimg<<<dim3(16,16),128,0,stream>>>(img, Wx, parts);
  k_prep<<<128,512,0,stream>>>(parts, bls, blog, P, glp, gfin, glen, bamax);

  if (f32){
    for (int t=0;t<TDEC;t++){
      k_stepA<<<NZB,512,0,stream>>>(a,t);
      k_stepB<0><<<NLB,512,0,stream>>>(a,t);
    }
    k_fin<<<1,512,0,stream>>>(a);
    k_gather<0><<<NROWS,512,0,stream>>>(Lst,rowsrc,rowamax,bamax,blog,out);
  } else {
    for (int t=0;t<TDEC;t++){
      k_stepA<<<NZB,512,0,stream>>>(a,t);
      k_stepB<1><<<NLB,512,0,stream>>>(a,t);
    }
    k_fin<<<1,512,0,stream>>>(a);
    k_gather<1><<<NROWS,512,0,stream>>>(Lst,rowsrc,rowamax,bamax,blog,out);
  }
}

// Round 11
// 2608.173 us; speedup vs baseline: 3.9175x; 2.9771x over previous
//
#include <hip/hip_runtime.h>
#include <hip/hip_bf16.h>
#include <math.h>

#define NB   32
#define FDIM 2048
#define VV   12000
#define DWW  300
#define HH   512
#define KW   3
#define TDEC 32
#define SEQ  33
#define NK   96
#define G4   2048
#define START_ID 1
#define END_ID   2
#define NROWS 3168
#define NLB   188
#define INTMX 0x7fffffff
#define FLOORF (-3.0e38f)

typedef float f4v __attribute__((ext_vector_type(4)));
__device__ __forceinline__ void nt_store4(float* p, float4 v){
  f4v t; t.x=v.x; t.y=v.y; t.z=v.z; t.w=v.w;
  __builtin_nontemporal_store(t, (f4v*)p);
}

__device__ __forceinline__ float sigf(float x){ return 1.0f/(1.0f+expf(-x)); }

__device__ __forceinline__ unsigned short f2b(float x){
  __hip_bfloat16 b = __float2bfloat16(x);
  return *reinterpret_cast<unsigned short*>(&b);
}

// insert (v,i) into sorted-desc top3; tie -> smaller index wins
__device__ __forceinline__ void ins3(float v, int i, float tv[3], int ti[3]){
  if (v > tv[0] || (v == tv[0] && i < ti[0])){
    tv[2]=tv[1]; ti[2]=ti[1]; tv[1]=tv[0]; ti[1]=ti[0]; tv[0]=v; ti[0]=i;
  } else if (v > tv[1] || (v == tv[1] && i < ti[1])){
    tv[2]=tv[1]; ti[2]=ti[1]; tv[1]=v; ti[1]=i;
  } else if (v > tv[2] || (v == tv[2] && i < ti[2])){
    tv[2]=v; ti[2]=i;
  }
}

struct SArgs {
  const float *E, *Wx, *Wh, *Wl, *blog;
  float *P, *c2, *h2s, *zp, *partA, *beam_lp, *rowamax;
  int *prev, *finished, *lengths, *parst, *rowsrc;
  void *Lst;
};

// ---------------- P_img = img @ Wx[300:,:] (into zp as scratch) ----------------
__global__ __launch_bounds__(128) void k_pimg(const float* __restrict__ img,
                                              const float* __restrict__ Wx,
                                              float* __restrict__ parts)
{
  int colb = blockIdx.x, fb = blockIdx.y, tid = threadIdx.x;
  int col = colb*128 + tid;
  int f0 = fb*128;
  __shared__ float s_img[32][128];
  for (int r=0;r<32;r++) s_img[r][tid] = img[r*FDIM + f0 + tid];
  __syncthreads();
  float acc[32];
  #pragma unroll
  for (int r=0;r<32;r++) acc[r]=0.f;
  for (int f2=0; f2<128; ++f2){
    float w = Wx[(size_t)(DWW + f0 + f2)*G4 + col];
    #pragma unroll
    for (int r=0;r<32;r++) acc[r] += w * s_img[r][f2];
  }
  #pragma unroll
  for (int r=0;r<32;r++) parts[(size_t)fb*(32*G4) + r*G4 + col] = acc[r];
}

// ---------------- prep: P reduce + state init + bamax ----------------
__global__ __launch_bounds__(512) void k_prep(const float* __restrict__ parts,
    const float* __restrict__ bls, const float* __restrict__ blog,
    float* __restrict__ P, float* __restrict__ beam_lp, int* __restrict__ prev,
    int* __restrict__ finished, int* __restrict__ lengths, float* __restrict__ bamax)
{
  int bid = blockIdx.x, tid = threadIdx.x;
  int gid = bid*512 + tid;
  float s = bls[gid & (G4-1)];
  for (int fb=0; fb<16; ++fb) s += parts[(size_t)fb*(32*G4) + gid];
  P[gid] = s;
  if (bid==0 && tid<NK){
    beam_lp[tid] = (tid%KW==0)?0.f:-1e9f;
    prev[tid]=START_ID; finished[tid]=0; lengths[tid]=0;
  }
  if (bid==2){
    __shared__ float s_rf[8]; __shared__ int s_ri[8];
    float bv=FLOORF; int bi=INTMX;
    for (int i=tid;i<VV;i+=512){
      float v=blog[i];
      if (v>bv || (v==bv && i<bi)){ bv=v; bi=i; }
    }
    #pragma unroll
    for (int d=1;d<64;d<<=1){
      float ov=__shfl_xor(bv,d); int oi=__shfl_xor(bi,d);
      if (ov>bv || (ov==bv && oi<bi)){ bv=ov; bi=oi; }
    }
    if ((tid&63)==0){ s_rf[tid>>6]=bv; s_ri[tid>>6]=bi; }
    __syncthreads();
    if (tid==0){
      for (int w=1;w<8;w++)
        if (s_rf[w]>bv || (s_rf[w]==bv && s_ri[w]<bi)){ bv=s_rf[w]; bi=s_ri[w]; }
      bamax[0] = (float)bi;
    }
  }
}

// ---------------- k_z: z-GEMM partials (K-split 8 x 32 colblocks, 256 blocks) ------
__global__ __launch_bounds__(512) void k_z(SArgs a, int t)
{
  int bid = blockIdx.x, tid = threadIdx.x;
  __shared__ float smem[96*17 + 16*64];
  __shared__ int sprev[NK], spar[NK];
  if (t>0 && tid<NK){ sprev[tid]=a.prev[tid]; spar[tid]=a.parst[(t-1)*NK+tid]; }
  __syncthreads();

  int colblk = bid & 31, p = bid >> 5;
  int col0 = colblk*64;
  int ks = p*104, ke = ks+104; if (ke>812) ke=812;
  float* sA = smem;            // 96*17
  float* sB = smem + 96*17;    // 16*64
  int tx = tid&15, ty = tid>>4;
  float4 acc[3];
  #pragma unroll
  for (int r=0;r<3;r++) acc[r]=make_float4(0.f,0.f,0.f,0.f);
  for (int k0=ks;k0<ke;k0+=16){
    int bk = ke-k0; if (bk>16) bk=16;
    for (int i=tid;i<96*16;i+=512){
      int n=i>>4, kk=i&15;
      float v=0.f;
      if (kk<bk){
        int kg=k0+kk;
        if (kg<DWW){
          int w = (t==0)?START_ID:sprev[n];
          v = a.E[(size_t)w*DWW+kg];
        } else if (t>0){
          v = a.h2s[((size_t)(t-1)*NK + spar[n])*HH + (kg-DWW)];
        }
      }
      sA[n*17+kk]=v;
    }
    for (int i=tid;i<16*64;i+=512){
      int kk=i>>6, cc=i&63;
      float v=0.f;
      if (kk<bk){
        int kg=k0+kk;
        v = (kg<DWW) ? a.Wx[(size_t)kg*G4+col0+cc] : a.Wh[(size_t)(kg-DWW)*G4+col0+cc];
      }
      sB[i]=v;
    }
    __syncthreads();
    #pragma unroll
    for (int kk=0;kk<16;++kk){
      float4 b4 = *(const float4*)&sB[kk*64+tx*4];
      #pragma unroll
      for (int rr=0;rr<3;rr++){
        float av = sA[(ty+rr*32)*17+kk];
        acc[rr].x += av*b4.x; acc[rr].y += av*b4.y;
        acc[rr].z += av*b4.z; acc[rr].w += av*b4.w;
      }
    }
    __syncthreads();
  }
  float* zpp = a.zp + (size_t)p*NK*G4;
  #pragma unroll
  for (int rr=0;rr<3;rr++)
    *(float4*)&zpp[(size_t)(ty+rr*32)*G4 + col0 + tx*4] = acc[rr];
}

// ---------------- k_g: gates (96 blocks, one row each) ----------------
__global__ __launch_bounds__(512) void k_g(SArgs a, int t)
{
  int n = blockIdx.x, m = threadIdx.x;
  int bb = n/KW;
  int par = (t>0) ? a.parst[(t-1)*NK + n] : 0;
  const float* Pr = a.P + (size_t)bb*G4;
  float zi=Pr[m], zf=Pr[HH+m], zg=Pr[2*HH+m], zo=Pr[3*HH+m];
  for (int p=0;p<8;p++){
    const float* zz = a.zp + (size_t)p*NK*G4 + (size_t)n*G4;
    zi+=zz[m]; zf+=zz[HH+m]; zg+=zz[2*HH+m]; zo+=zz[3*HH+m];
  }
  float cold = (t==0) ? 0.f : a.c2[(size_t)((t-1)&1)*NK*HH + (size_t)par*HH + m];
  float c2v = sigf(zf+1.0f)*cold + sigf(zi)*tanhf(zg);
  float h2v = sigf(zo)*tanhf(c2v);
  a.c2[(size_t)(t&1)*NK*HH + (size_t)n*HH + m] = c2v;
  a.h2s[((size_t)t*NK+n)*HH + m] = h2v;
}

// ---------------- k_l: logits GEMM + records + Lst (188 blocks) ----------------
template<int BF>
__global__ __launch_bounds__(512) void k_l(SArgs a, int t)
{
  __shared__ float smem[96*36 + 32*64];
  const int bid = blockIdx.x, tid = threadIdx.x;
  const int col0 = bid*64;
  float* sAl = smem;
  float* sBl = smem + 96*36;
  const int tx=tid&15, ty=tid>>4;
  float4 acc[3];
  #pragma unroll
  for (int r=0;r<3;r++) acc[r]=make_float4(0.f,0.f,0.f,0.f);
  for (int k0=0;k0<HH;k0+=32){
    for (int i=tid;i<768;i+=512){
      int row=i>>3, kq=(i&7)*4;
      *(float4*)&sAl[row*36+kq] = *(const float4*)&a.h2s[((size_t)t*NK+row)*HH + k0+kq];
    }
    {
      int kk=tid>>4, c4=(tid&15)*4;
      int col=col0+c4;
      float4 v = make_float4(0.f,0.f,0.f,0.f);
      if (col < VV) v = *(const float4*)&a.Wl[(size_t)(k0+kk)*VV+col];
      *(float4*)&sBl[kk*64+c4]=v;
    }
    __syncthreads();
    #pragma unroll
    for (int kk=0;kk<32;++kk){
      float4 b4 = *(const float4*)&sBl[kk*64+tx*4];
      #pragma unroll
      for (int rr=0;rr<3;rr++){
        float av = sAl[(ty+rr*32)*36+kk];
        acc[rr].x += av*b4.x; acc[rr].y += av*b4.y;
        acc[rr].z += av*b4.z; acc[rr].w += av*b4.w;
      }
    }
    __syncthreads();
  }
  int colg = col0 + tx*4;
  bool cval = colg < VV;
  float4 bias = make_float4(0.f,0.f,0.f,0.f);
  if (cval) bias = *(const float4*)&a.blog[colg];
  #pragma unroll
  for (int rr=0;rr<3;rr++){
    int row = ty + rr*32;
    float v0,v1,v2,v3;
    if (cval){
      v0=acc[rr].x+bias.x; v1=acc[rr].y+bias.y;
      v2=acc[rr].z+bias.z; v3=acc[rr].w+bias.w;
      size_t off = (size_t)(t*NK+row)*VV + colg;
      if (BF){
        ushort4 u;
        u.x=f2b(v0); u.y=f2b(v1); u.z=f2b(v2); u.w=f2b(v3);
        *(ushort4*)((unsigned short*)a.Lst + off) = u;
      } else {
        nt_store4((float*)a.Lst + off, make_float4(v0,v1,v2,v3));
      }
    } else { v0=v1=v2=v3=-INFINITY; }
    float m = fmaxf(fmaxf(v0,v1),fmaxf(v2,v3));
    #pragma unroll
    for (int d=1;d<16;d<<=1) m = fmaxf(m,__shfl_xor(m,d));
    float tv[3]={-INFINITY,-INFINITY,-INFINITY};
    int   ti[3]={INTMX,INTMX,INTMX};
    float s=0.f;
    if (cval){
      ins3(v0,colg,tv,ti); ins3(v1,colg+1,tv,ti);
      ins3(v2,colg+2,tv,ti); ins3(v3,colg+3,tv,ti);
      s = expf(v0-m)+expf(v1-m)+expf(v2-m)+expf(v3-m);
    }
    #pragma unroll
    for (int d=1;d<16;d<<=1){
      s += __shfl_xor(s,d);
      float p0=__shfl_xor(tv[0],d),p1=__shfl_xor(tv[1],d),p2=__shfl_xor(tv[2],d);
      int q0=__shfl_xor(ti[0],d),q1=__shfl_xor(ti[1],d),q2=__shfl_xor(ti[2],d);
      ins3(p0,q0,tv,ti); ins3(p1,q1,tv,ti); ins3(p2,q2,tv,ti);
    }
    if (tx==0){
      float* rp = a.partA + ((size_t)row*NLB + bid)*8;
      *(float4*)rp = make_float4(m,s,tv[0],tv[1]);
      *((float4*)rp+1) = make_float4(tv[2],__int_as_float(ti[0]),__int_as_float(ti[1]),__int_as_float(ti[2]));
    }
  }
}

// ---------------- k_s: beam select (32 blocks, one batch each) ----------------
__global__ __launch_bounds__(512) void k_s(SArgs a, int t)
{
  __shared__ float s_lse[KW], s_tv3[KW*3];
  __shared__ int   s_ti3[KW*3];
  int b = blockIdx.x, tid = threadIdx.x;
  int wv = tid>>6, lane = tid&63;
  if (wv < KW){
    int n = b*KW+wv;
    float M=FLOORF, S=0.f;
    float tv[3]={FLOORF,FLOORF,FLOORF}; int ti[3]={INTMX,INTMX,INTMX};
    for (int i=lane;i<NLB;i+=64){
      const float* rp = a.partA + ((size_t)n*NLB+i)*8;
      float4 r0=*(const float4*)rp, r1=*((const float4*)rp+1);
      float nm = fmaxf(M,r0.x);
      S = S*expf(M-nm) + r0.y*expf(r0.x-nm);
      M = nm;
      ins3(r0.z,__float_as_int(r1.y),tv,ti);
      ins3(r0.w,__float_as_int(r1.z),tv,ti);
      ins3(r1.x,__float_as_int(r1.w),tv,ti);
    }
    #pragma unroll
    for (int d=1;d<64;d<<=1){
      float Mo=__shfl_xor(M,d), So=__shfl_xor(S,d);
      float nm=fmaxf(M,Mo);
      S = S*expf(M-nm)+So*expf(Mo-nm);
      M=nm;
      float p0=__shfl_xor(tv[0],d),p1=__shfl_xor(tv[1],d),p2=__shfl_xor(tv[2],d);
      int q0=__shfl_xor(ti[0],d),q1=__shfl_xor(ti[1],d),q2=__shfl_xor(ti[2],d);
      ins3(p0,q0,tv,ti); ins3(p1,q1,tv,ti); ins3(p2,q2,tv,ti);
    }
    if (lane==0){
      s_lse[wv] = M + logf(S);
      #pragma unroll
      for (int j=0;j<3;j++){ s_tv3[wv*3+j]=tv[j]; s_ti3[wv*3+j]=ti[j]; }
      a.rowamax[t*NK+n] = (float)ti[0];
    }
  }
  __syncthreads();
  if (tid==0){
    float cv[3]={FLOORF,FLOORF,FLOORF}; int cf[3]={INTMX,INTMX,INTMX};
    for (int k=0;k<KW;k++){
      int n=b*KW+k;
      if (a.finished[n]){
        ins3(a.beam_lp[n], k*VV+END_ID, cv,cf);
      } else {
        float blp=a.beam_lp[n], lse=s_lse[k];
        for (int j=0;j<3;j++)
          ins3(blp + (s_tv3[k*3+j]-lse), k*VV+s_ti3[k*3+j], cv,cf);
      }
    }
    int fin_old[KW], len_old[KW];
    for (int j=0;j<KW;j++){ fin_old[j]=a.finished[b*KW+j]; len_old[j]=a.lengths[b*KW+j]; }
    for (int kp=0;kp<KW;kp++){
      int par=cf[kp]/VV, word=cf[kp]-par*VV;
      a.beam_lp[b*KW+kp]=cv[kp];
      a.prev[b*KW+kp]=word;
      a.parst[t*NK + b*KW+kp] = b*KW+par;
      int fp=fin_old[par];
      a.lengths[b*KW+kp] = fp?len_old[par]:(len_old[par]+1);
      a.finished[b*KW+kp] = fp | (word==END_ID);
    }
  }
}

// ---------------- backtrack ancestors -> rowsrc map ----------------
__global__ __launch_bounds__(128) void k_backtrack(const int* __restrict__ parst,
                                                   const int* __restrict__ lengths,
                                                   int* __restrict__ rowsrc)
{
  int n = threadIdx.x;
  if (n >= NK) return;
  int b = n / KW;
  int len = lengths[n];
  rowsrc[n*SEQ + TDEC] = -1;
  int a = n;
  for (int tau = TDEC-1; tau >= 1; --tau){
    int p = parst[tau*NK + a];
    rowsrc[n*SEQ + tau] = (tau < len) ? (tau*NK + p) : -1;
    a = p;
  }
  rowsrc[n*SEQ + 0] = b*KW;
}

// ---------------- gather: out rows from stored decode logits ----------------
template<int BF>
__global__ __launch_bounds__(512) void k_gather(const void* __restrict__ Lst,
    const int* __restrict__ rowsrc, const float* __restrict__ rowamax,
    const float* __restrict__ bamax, const float* __restrict__ blog,
    float* __restrict__ out)
{
  int row = blockIdx.x, tid = threadIdx.x;
  int src = rowsrc[row];
  float* orow = out + (size_t)row*VV;
  if (src >= 0){
    if (BF){
      const unsigned short* L = (const unsigned short*)Lst + (size_t)src*VV;
      for (int j=tid;j<VV/4;j+=512){
        ushort4 u = *(const ushort4*)&L[j*4];
        float4 v;
        v.x = __uint_as_float(((unsigned)u.x)<<16);
        v.y = __uint_as_float(((unsigned)u.y)<<16);
        v.z = __uint_as_float(((unsigned)u.z)<<16);
        v.w = __uint_as_float(((unsigned)u.w)<<16);
        nt_store4(&orow[j*4], v);
      }
    } else {
      const float* L = (const float*)Lst + (size_t)src*VV;
      for (int j=tid;j<VV/4;j+=512){
        float4 v = *(const float4*)&L[j*4];
        nt_store4(&orow[j*4], v);
      }
    }
    if (tid==0) out[(size_t)NROWS*VV + row] = rowamax[src];
  } else {
    for (int j=tid;j<VV/4;j+=512){
      float4 v = *(const float4*)&blog[j*4];
      nt_store4(&orow[j*4], v);
    }
    if (tid==0) out[(size_t)NROWS*VV + row] = bamax[0];
  }
}

extern "C" void kernel_launch(void* const* d_in, const int* in_sizes, int n_in,
                              void* d_out, int out_size, void* d_ws, size_t ws_size,
                              hipStream_t stream) {
  (void)in_sizes; (void)n_in; (void)out_size;
  const float* img  = (const float*)d_in[0];
  const float* E    = (const float*)d_in[1];
  const float* Wx   = (const float*)d_in[2];
  const float* Wh   = (const float*)d_in[3];
  const float* bls  = (const float*)d_in[4];
  const float* Wl   = (const float*)d_in[5];
  const float* blog = (const float*)d_in[6];
  float* out = (float*)d_out;

  float* ws = (float*)d_ws;
  size_t o = 0;
  float* P       = ws+o; o += (size_t)NB*G4;         // 65536
  float* c2      = ws+o; o += (size_t)2*NK*HH;       // double buffer
  float* h2s     = ws+o; o += (size_t)TDEC*NK*HH;    // per-step h2
  float* zp      = ws+o; o += (size_t)8*NK*G4;       // z partials / pimg parts
  float* partA   = ws+o; o += (size_t)NK*NLB*8;
  float* beam_lp = ws+o; o += 128;
  float* rowamax = ws+o; o += (size_t)TDEC*NK;
  float* bamax   = ws+o; o += 4;
  int* prev      = (int*)(ws+o); o += 128;
  int* finished  = (int*)(ws+o); o += 128;
  int* lengths   = (int*)(ws+o); o += 128;
  int* parst     = (int*)(ws+o); o += (size_t)TDEC*NK;
  int* rowsrc    = (int*)(ws+o); o += 3328;
  o = (o+3) & ~(size_t)3;
  void* Lst      = (void*)(ws+o);

  bool f32 = (ws_size/4 > o) && ((ws_size/4 - o) >= (size_t)TDEC*NK*VV);

  SArgs a;
  a.E=E; a.Wx=Wx; a.Wh=Wh; a.Wl=Wl; a.blog=blog;
  a.P=P; a.c2=c2; a.h2s=h2s; a.zp=zp; a.partA=partA;
  a.beam_lp=beam_lp; a.rowamax=rowamax;
  a.prev=prev; a.finished=finished; a.lengths=lengths; a.parst=parst; a.rowsrc=rowsrc;
  a.Lst=Lst;

  k_pimg<<<dim3(16,16),128,0,stream>>>(img, Wx, zp);
  k_prep<<<128,512,0,stream>>>(zp, bls, blog, P, beam_lp, prev, finished, lengths, bamax);

  if (f32){
    for (int t=0;t<TDEC;t++){
      k_z<<<256,512,0,stream>>>(a,t);
      k_g<<<NK,512,0,stream>>>(a,t);
      k_l<0><<<NLB,512,0,stream>>>(a,t);
      k_s<<<NB,512,0,stream>>>(a,t);
    }
    k_backtrack<<<1,128,0,stream>>>(parst, lengths, rowsrc);
    k_gather<0><<<NROWS,512,0,stream>>>(Lst,rowsrc,rowamax,bamax,blog,out);
  } else {
    for (int t=0;t<TDEC;t++){
      k_z<<<256,512,0,stream>>>(a,t);
      k_g<<<NK,512,0,stream>>>(a,t);
      k_l<1><<<NLB,512,0,stream>>>(a,t);
      k_s<<<NB,512,0,stream>>>(a,t);
    }
    k_backtrack<<<1,128,0,stream>>>(parst, lengths, rowsrc);
    k_gather<1><<<NROWS,512,0,stream>>>(Lst,rowsrc,rowamax,bamax,blog,out);
  }
}